// Round 2
// baseline (565.707 us; speedup 1.0000x reference)
//
#include <hip/hip_runtime.h>
#include <cmath>

// Bahdanau attention, MI355X. B=32, T=8192, D=256, U=128, fp32.
// Round 2: single pass over values (268 MB HBM floor ~43us).
//  - score_ctx: 64-row chunk as 2x32-row halves (online softmax rescale),
//    LDS ~34KB -> 4 blocks/CU (16 waves). bf16 hi/lo split MFMA (3 terms)
//    for fp32-grade scores; fast tanh via v_exp+v_rcp; vectorized ctx
//    partial (b128 LDS reads, register acc, LDS tree reduce into aliased
//    A-buffer).
//  - finalize split into 3 parallel kernels (stats / attn / ctx combine).

#define B_ 32
#define T_ 8192
#define D_ 256
#define U_ 128
#define CH_ 64             // t-rows per block (2 halves of 32)
#define NCH_ (T_ / CH_)    // 128 chunks per batch
#define GRP_ 520           // ushort stride per (mt,kk) group: 64*8 + 8 pad

typedef float f32x4 __attribute__((ext_vector_type(4)));
typedef short s16x8 __attribute__((ext_vector_type(8)));
typedef __bf16 bf16x8 __attribute__((ext_vector_type(8)));

__device__ __forceinline__ unsigned short f2bf(float x) {
    unsigned u = __builtin_bit_cast(unsigned, x);
    u += 0x7fffu + ((u >> 16) & 1u);     // RNE
    return (unsigned short)(u >> 16);
}
__device__ __forceinline__ float bf2f(unsigned short s) {
    return __builtin_bit_cast(float, ((unsigned)s) << 16);
}
__device__ __forceinline__ float bf2f_s(short s) {
    return bf2f((unsigned short)s);
}
// tanh(x) = 1 - 2/(e^2x + 1); exact limits, ~1e-7 rel err, no NaN.
__device__ __forceinline__ float tanh_fast(float x) {
    float e = __expf(2.f * x);
    return 1.f - 2.f * __builtin_amdgcn_rcpf(e + 1.f);
}

// ---------------- k0: W1 -> hi/lo bf16 in B-fragment layout ----------------
// frag element idx = ((kk*8+nn)*64 + lane)*8 + j
// maps to W1[k][n], k = kk*32 + (lane>>4)*8 + j, n = nn*16 + (lane&15)
__global__ void prep_w1(const float* __restrict__ W1,
                        unsigned short* __restrict__ W1h,
                        unsigned short* __restrict__ W1l) {
    int idx = blockIdx.x * 256 + threadIdx.x;   // 32768 total
    int j = idx & 7, lane = (idx >> 3) & 63, nn = (idx >> 9) & 7, kk = idx >> 12;
    int k = kk * 32 + (lane >> 4) * 8 + j;
    int n = nn * 16 + (lane & 15);
    float w = W1[k * U_ + n];
    unsigned short hi = f2bf(w);
    W1h[idx] = hi;
    W1l[idx] = f2bf(w - bf2f(hi));
}

// ---------------- k1: h_q = relu(query @ W2 + b2) ----------------
__global__ void prep_hq(const float* __restrict__ query, const float* __restrict__ W2,
                        const float* __restrict__ W2b, float* __restrict__ hq) {
    int b = blockIdx.x, u = threadIdx.x;
    float acc = W2b[u];
    const float* q = query + b * D_;
    for (int d = 0; d < D_; ++d) acc = fmaf(q[d], W2[d * U_ + u], acc);
    hq[b * U_ + u] = fmaxf(acc, 0.f);
}

// ---------------- k2: fused scores + chunk softmax + partial context -------
__global__ __launch_bounds__(256, 4) void score_ctx(
    const float* __restrict__ values,
    const unsigned short* __restrict__ W1h, const unsigned short* __restrict__ W1l,
    const float* __restrict__ hq, const float* __restrict__ b1,
    const float* __restrict__ Vk,
    float* __restrict__ scores, float* __restrict__ stats, float* __restrict__ ctxp)
{
    __shared__ __align__(16) unsigned short Ah[16 * GRP_];   // 16640 B
    __shared__ __align__(16) unsigned short Al[16 * GRP_];   // 16640 B
    __shared__ float scp[4][32];
    __shared__ float esc[32];
    __shared__ float m_s, l_s, alpha_s;

    const int tid = threadIdx.x;
    const int b = blockIdx.x >> 7;      // NCH_=128 chunks
    const int c = blockIdx.x & 127;
    const int t0 = c * CH_;
    const int lane = tid & 63;
    const int w = tid >> 6;
    const int part = tid >> 5;          // 0..7
    const int dgrp = tid & 31;          // 0..31 (8 d's each)
    const int ckk = dgrp >> 2, cg = dgrp & 3;

    if (tid == 0) { m_s = -1e30f; l_s = 0.f; }

    // epilogue constants (wave w owns unit tiles 2w, 2w+1)
    const int u0 = lane & 15;
    float b1v[2], hqv[2], Vv[2];
#pragma unroll
    for (int q = 0; q < 2; ++q) {
        int u = (2 * w + q) * 16 + u0;
        b1v[q] = b1[u];
        hqv[q] = hq[b * U_ + u];
        Vv[q] = Vk[u];
    }

    float c8[8];
#pragma unroll
    for (int j = 0; j < 8; ++j) c8[j] = 0.f;

    for (int h = 0; h < 2; ++h) {
        __syncthreads();   // prev half's ctx reads (and m_s init) done
        // ---- stage 32x256 fp32 -> bf16 hi/lo in A-fragment layout ----
        {
            const float* src = values + ((size_t)b * T_ + t0 + h * 32) * D_;
#pragma unroll
            for (int it = 0; it < 4; ++it) {
                int row = it * 8 + (tid >> 5);      // 0..31
                int col = (tid & 31) * 8;           // 0..248
                const float* p = src + row * D_ + col;
                float4 x0 = *(const float4*)p;
                float4 x1 = *(const float4*)(p + 4);
                float xs[8] = {x0.x, x0.y, x0.z, x0.w, x1.x, x1.y, x1.z, x1.w};
                s16x8 hv, lv;
#pragma unroll
                for (int e = 0; e < 8; ++e) {
                    __bf16 hb = (__bf16)xs[e];
                    float hf = (float)hb;
                    __bf16 lb = (__bf16)(xs[e] - hf);
                    hv[e] = __builtin_bit_cast(short, hb);
                    lv[e] = __builtin_bit_cast(short, lb);
                }
                int mt = row >> 4, m = row & 15;
                int kk = col >> 5, g = (col >> 3) & 3;
                int off = (mt * 8 + kk) * GRP_ + (g * 16 + m) * 8;
                *(s16x8*)&Ah[off] = hv;
                *(s16x8*)&Al[off] = lv;
            }
        }
        __syncthreads();

        // ---- MFMA: wave w owns N-tiles {2w,2w+1}; mt in {0,1} ----
        f32x4 acc[2][2];
#pragma unroll
        for (int mt = 0; mt < 2; ++mt)
#pragma unroll
            for (int q = 0; q < 2; ++q) acc[mt][q] = (f32x4){0.f, 0.f, 0.f, 0.f};

#pragma unroll
        for (int kk = 0; kk < 8; ++kk) {
            bf16x8 bh[2], bl[2];
#pragma unroll
            for (int q = 0; q < 2; ++q) {
                int nn = 2 * w + q;
                int boff = ((kk * 8 + nn) * 64 + lane) * 8;
                bh[q] = __builtin_bit_cast(bf16x8, *(const s16x8*)&W1h[boff]);
                bl[q] = __builtin_bit_cast(bf16x8, *(const s16x8*)&W1l[boff]);
            }
#pragma unroll
            for (int mt = 0; mt < 2; ++mt) {
                int aoff = (mt * 8 + kk) * GRP_ + lane * 8;
                bf16x8 ah = __builtin_bit_cast(bf16x8, *(const s16x8*)&Ah[aoff]);
                bf16x8 al = __builtin_bit_cast(bf16x8, *(const s16x8*)&Al[aoff]);
#pragma unroll
                for (int q = 0; q < 2; ++q) {
                    acc[mt][q] = __builtin_amdgcn_mfma_f32_16x16x32_bf16(ah, bh[q], acc[mt][q], 0, 0, 0);
                    acc[mt][q] = __builtin_amdgcn_mfma_f32_16x16x32_bf16(ah, bl[q], acc[mt][q], 0, 0, 0);
                    acc[mt][q] = __builtin_amdgcn_mfma_f32_16x16x32_bf16(al, bh[q], acc[mt][q], 0, 0, 0);
                }
            }
        }

        // ---- epilogue: per-wave partial scores over its 32 units ----
#pragma unroll
        for (int mt = 0; mt < 2; ++mt) {
            float p[4];
#pragma unroll
            for (int i = 0; i < 4; ++i) {
                float z = 0.f;
#pragma unroll
                for (int q = 0; q < 2; ++q) {
                    float hpre = fmaxf(acc[mt][q][i] + b1v[q], 0.f) + hqv[q];
                    z += tanh_fast(hpre) * Vv[q];
                }
                p[i] = z;
            }
#pragma unroll
            for (int off = 1; off < 16; off <<= 1)
#pragma unroll
                for (int i = 0; i < 4; ++i) p[i] += __shfl_xor(p[i], off, 16);
            if (u0 == 0) {
                int base = mt * 16 + (lane >> 4) * 4;
#pragma unroll
                for (int i = 0; i < 4; ++i) scp[w][base + i] = p[i];
            }
        }
        __syncthreads();

        // ---- online softmax stats for this half (one 32-lane group) ----
        if (tid < 32) {
            float s = scp[0][tid] + scp[1][tid] + scp[2][tid] + scp[3][tid];
            scores[b * T_ + t0 + h * 32 + tid] = s;
            float mh = s;
#pragma unroll
            for (int off = 16; off >= 1; off >>= 1)
                mh = fmaxf(mh, __shfl_xor(mh, off, 32));
            float m_old = m_s;
            float m_new = fmaxf(m_old, mh);
            float e = __expf(s - m_new);
            esc[tid] = e;
            float lh = e;
#pragma unroll
            for (int off = 16; off >= 1; off >>= 1)
                lh += __shfl_xor(lh, off, 32);
            if (tid == 0) {
                float al = __expf(m_old - m_new);
                alpha_s = al;
                l_s = l_s * al + lh;
                m_s = m_new;
            }
        }
        __syncthreads();

        // ---- ctx accumulate: thread owns 4 t's x 8 d's ----
        {
            float al = alpha_s;
#pragma unroll
            for (int j = 0; j < 8; ++j) c8[j] *= al;
#pragma unroll
            for (int i = 0; i < 4; ++i) {
                int tl = part * 4 + i;              // 0..31
                int mt = tl >> 4, m = tl & 15;
                int off = (mt * 8 + ckk) * GRP_ + (cg * 16 + m) * 8;
                float e = esc[tl];
                s16x8 hv = *(const s16x8*)&Ah[off];
                s16x8 lv = *(const s16x8*)&Al[off];
#pragma unroll
                for (int j = 0; j < 8; ++j)
                    c8[j] = fmaf(e, bf2f_s(hv[j]) + bf2f_s(lv[j]), c8[j]);
            }
        }
    }

    // ---- reduce ctx across the 8 t-parts (alias dead A-buffer) ----
    __syncthreads();
    float* red = (float*)Ah;                 // 8*256*4 = 8192 B <= 16640 B
#pragma unroll
    for (int j = 0; j < 8; ++j) red[part * 256 + dgrp * 8 + j] = c8[j];
    __syncthreads();
    {
        float s = 0.f;
#pragma unroll
        for (int p = 0; p < 8; ++p) s += red[p * 256 + tid];
        ctxp[((size_t)(b * NCH_ + c)) * D_ + tid] = s;
    }
    if (tid == 0) {
        stats[(b * NCH_ + c) * 2 + 0] = m_s;
        stats[(b * NCH_ + c) * 2 + 1] = l_s;
    }
}

// ---------------- k3a: per-batch global softmax stats ----------------
__global__ void combine_stats(const float* __restrict__ stats, float* __restrict__ Msum)
{
    __shared__ float wm[2], wl[2];
    int b = blockIdx.x, tid = threadIdx.x;   // 128 threads
    float m = stats[(b * NCH_ + tid) * 2 + 0];
    float l = stats[(b * NCH_ + tid) * 2 + 1];
    float mm = m;
#pragma unroll
    for (int off = 32; off >= 1; off >>= 1) mm = fmaxf(mm, __shfl_xor(mm, off, 64));
    if ((tid & 63) == 0) wm[tid >> 6] = mm;
    __syncthreads();
    float M = fmaxf(wm[0], wm[1]);
    float lw = l * __expf(m - M);
#pragma unroll
    for (int off = 32; off >= 1; off >>= 1) lw += __shfl_xor(lw, off, 64);
    if ((tid & 63) == 0) wl[tid >> 6] = lw;
    __syncthreads();
    if (tid == 0) {
        Msum[b * 2 + 0] = M;
        Msum[b * 2 + 1] = 1.f / (wl[0] + wl[1]);
    }
}

// ---------------- k3b: attention weights ----------------
__global__ void attn_out(const float* __restrict__ scores, const float* __restrict__ Msum,
                         float* __restrict__ out)
{
    int b = blockIdx.x >> 3, s8 = blockIdx.x & 7;
    float M = Msum[b * 2 + 0], invL = Msum[b * 2 + 1];
    int t = s8 * 1024 + threadIdx.x * 4;
    float4 s4 = *(const float4*)&scores[b * T_ + t];
    float4 r;
    r.x = __expf(s4.x - M) * invL;
    r.y = __expf(s4.y - M) * invL;
    r.z = __expf(s4.z - M) * invL;
    r.w = __expf(s4.w - M) * invL;
    *(float4*)&out[B_ * D_ + (size_t)b * T_ + t] = r;
}

// ---------------- k3c: context combine ----------------
__global__ void ctx_out(const float* __restrict__ ctxp, const float* __restrict__ stats,
                        const float* __restrict__ Msum, float* __restrict__ out)
{
    __shared__ float red[8 * 256];
    int b = blockIdx.x, tid = threadIdx.x;
    int part = tid >> 5, dgrp = tid & 31;
    float M = Msum[b * 2 + 0], invL = Msum[b * 2 + 1];
    float a[8];
#pragma unroll
    for (int j = 0; j < 8; ++j) a[j] = 0.f;
    for (int c2 = part * 16; c2 < part * 16 + 16; ++c2) {
        float wc = __expf(stats[(b * NCH_ + c2) * 2 + 0] - M);
        const float* p = ctxp + ((size_t)(b * NCH_ + c2)) * D_ + dgrp * 8;
        float4 v0 = *(const float4*)p;
        float4 v1 = *(const float4*)(p + 4);
        a[0] = fmaf(wc, v0.x, a[0]); a[1] = fmaf(wc, v0.y, a[1]);
        a[2] = fmaf(wc, v0.z, a[2]); a[3] = fmaf(wc, v0.w, a[3]);
        a[4] = fmaf(wc, v1.x, a[4]); a[5] = fmaf(wc, v1.y, a[5]);
        a[6] = fmaf(wc, v1.z, a[6]); a[7] = fmaf(wc, v1.w, a[7]);
    }
#pragma unroll
    for (int j = 0; j < 8; ++j) red[part * 256 + dgrp * 8 + j] = a[j];
    __syncthreads();
    float s = 0.f;
#pragma unroll
    for (int p = 0; p < 8; ++p) s += red[p * 256 + tid];
    out[b * D_ + tid] = s * invL;
}

// ---------------- launch ----------------
extern "C" void kernel_launch(void* const* d_in, const int* in_sizes, int n_in,
                              void* d_out, int out_size, void* d_ws, size_t ws_size,
                              hipStream_t stream)
{
    const float* query = (const float*)d_in[0];
    const float* values = (const float*)d_in[1];
    const float* W1 = (const float*)d_in[2];
    const float* b1 = (const float*)d_in[3];
    const float* W2 = (const float*)d_in[4];
    const float* b2 = (const float*)d_in[5];
    const float* Vk = (const float*)d_in[6];
    // d_in[7] = V_bias: constant score shift, cancels in softmax.
    float* out = (float*)d_out;
    char* ws = (char*)d_ws;

    // ws layout (bytes), total 5,423,360
    float* scores = (float*)(ws + 0);                  // B*T*4       = 1048576
    float* hq     = (float*)(ws + 1048576);            // B*U*4       = 16384
    float* stats  = (float*)(ws + 1064960);            // B*128*2*4   = 32768
    float* ctxp   = (float*)(ws + 1097728);            // B*128*256*4 = 4194304
    unsigned short* W1h = (unsigned short*)(ws + 5292032);   // 65536
    unsigned short* W1l = (unsigned short*)(ws + 5357568);   // 65536
    float* Msum   = (float*)(ws + 5423104);            // B*2*4       = 256

    prep_w1<<<128, 256, 0, stream>>>(W1, W1h, W1l);
    prep_hq<<<B_, U_, 0, stream>>>(query, W2, b2, hq);
    score_ctx<<<B_ * NCH_, 256, 0, stream>>>(values, W1h, W1l, hq, b1, Vk,
                                             scores, stats, ctxp);
    combine_stats<<<B_, 128, 0, stream>>>(stats, Msum);
    attn_out<<<B_ * 8, 256, 0, stream>>>(scores, Msum, out);
    ctx_out<<<B_, 256, 0, stream>>>(ctxp, stats, Msum, out);
}

// Round 3
// 414.329 us; speedup vs baseline: 1.3654x; 1.3654x over previous
//
#include <hip/hip_runtime.h>
#include <cmath>

// Bahdanau attention, MI355X. B=32, T=8192, D=256, U=128, fp32.
// Round 3: single pass over values (268 MB HBM floor ~43us).
//  - score_ctx, launch_bounds(256,2): NO spills (r2's (256,4) forced 64 VGPR
//    -> 640 MB scratch traffic). LDS 34KB -> 4 blocks/CU.
//  - lane-aligned staging: thread stages exactly one A-frag lane (8 floats),
//    LDS writes at lane*16B = conflict-free.
//  - ctx partial via coalesced global re-read (L1/L2-hot), not transposed
//    LDS reads: kills remaining bank conflicts, 1-reg accumulator.
//  - 3 launches total: prep(W1 frags + hq), score_ctx, epilogue(attn+ctx).

#define B_ 32
#define T_ 8192
#define D_ 256
#define U_ 128
#define CH_ 64             // t-rows per block (2 halves of 32)
#define NCH_ (T_ / CH_)    // 128 chunks per batch
#define GRP_ 520           // ushort stride per (mt,kk) tile: 64*8 + 8 pad

typedef float f32x4 __attribute__((ext_vector_type(4)));
typedef short s16x8 __attribute__((ext_vector_type(8)));
typedef __bf16 bf16x8 __attribute__((ext_vector_type(8)));

// tanh(x) = 1 - 2/(e^2x + 1); exact limits, ~1e-7 rel err, no NaN.
__device__ __forceinline__ float tanh_fast(float x) {
    float e = __expf(2.f * x);
    return 1.f - 2.f * __builtin_amdgcn_rcpf(e + 1.f);
}

// ---------------- k0: prep W1 frags (blocks 0..127) + hq (blocks 128..159) --
// W1 frag element idx = ((kk*8+nn)*64 + lane)*8 + j
//   <-> W1[k][n], k = kk*32 + (lane>>4)*8 + j, n = nn*16 + (lane&15)
__global__ __launch_bounds__(256) void prep(
    const float* __restrict__ W1, const float* __restrict__ query,
    const float* __restrict__ W2, const float* __restrict__ b2,
    unsigned short* __restrict__ W1h, unsigned short* __restrict__ W1l,
    float* __restrict__ hq)
{
    int blk = blockIdx.x, tid = threadIdx.x;
    if (blk < 128) {
        int idx2 = blk * 256 + tid;          // coalesced W1 read
        int k = idx2 >> 7, n = idx2 & 127;
        float wv = W1[idx2];
        int kk = k >> 5, j = k & 7, lg = (k >> 3) & 3;
        int lane = lg * 16 + (n & 15);
        int nn = n >> 4;
        int pos = ((kk * 8 + nn) * 64 + lane) * 8 + j;
        __bf16 hb = (__bf16)wv;
        float hf = (float)hb;
        __bf16 lb = (__bf16)(wv - hf);
        W1h[pos] = __builtin_bit_cast(unsigned short, hb);
        W1l[pos] = __builtin_bit_cast(unsigned short, lb);
    } else {
        __shared__ float hq2[256];
        int b = blk - 128;
        int u = tid & 127, half = tid >> 7;
        float acc = half ? 0.f : b2[u];
        const float* q = query + b * D_ + half * 128;
        const float* w2 = W2 + (half * 128) * U_ + u;
        for (int d = 0; d < 128; ++d)
            acc = fmaf(q[d], w2[d * U_], acc);
        hq2[tid] = acc;
        __syncthreads();
        if (tid < 128) hq[b * U_ + tid] = fmaxf(hq2[tid] + hq2[tid + 128], 0.f);
    }
}

// ---------------- k1: fused scores + chunk softmax + partial context -------
__device__ __forceinline__ void stage_half(
    const float* __restrict__ src, int w, int lane,
    unsigned short* __restrict__ Ah, unsigned short* __restrict__ Al)
{
#pragma unroll
    for (int p = 0; p < 4; ++p) {
        int tile = w * 4 + p;                // 0..15
        int mt = tile >> 3, kk = tile & 7;
        const float* ptr = src + (mt * 16 + (lane & 15)) * D_ + kk * 32 + (lane >> 4) * 8;
        float4 x0 = *(const float4*)ptr;
        float4 x1 = *(const float4*)(ptr + 4);
        float xs[8] = {x0.x, x0.y, x0.z, x0.w, x1.x, x1.y, x1.z, x1.w};
        s16x8 hv, lv;
#pragma unroll
        for (int e = 0; e < 8; ++e) {
            __bf16 hb = (__bf16)xs[e];
            float hf = (float)hb;
            __bf16 lb = (__bf16)(xs[e] - hf);
            hv[e] = __builtin_bit_cast(short, hb);
            lv[e] = __builtin_bit_cast(short, lb);
        }
        int off = (mt * 8 + kk) * GRP_ + lane * 8;   // lane*16B: conflict-free
        *(s16x8*)&Ah[off] = hv;
        *(s16x8*)&Al[off] = lv;
    }
}

__global__ __launch_bounds__(256, 2) void score_ctx(
    const float* __restrict__ values,
    const unsigned short* __restrict__ W1h, const unsigned short* __restrict__ W1l,
    const float* __restrict__ hq, const float* __restrict__ b1,
    const float* __restrict__ Vk,
    float* __restrict__ sc_g, float* __restrict__ st_g, float* __restrict__ cp_g)
{
    __shared__ __align__(16) unsigned short Ah[16 * GRP_];   // 16640 B
    __shared__ __align__(16) unsigned short Al[16 * GRP_];   // 16640 B
    __shared__ float scp[4][32];
    __shared__ float esc[32];
    __shared__ float m_s, l_s, alpha_s;

    const int tid = threadIdx.x;
    const int b = blockIdx.x >> 7;      // NCH_=128 chunks
    const int c = blockIdx.x & 127;
    const int t0 = c * CH_;
    const int lane = tid & 63;
    const int w = tid >> 6;
    const int u0 = lane & 15;

    if (tid == 0) { m_s = -1e30f; l_s = 0.f; }

    // epilogue constants (wave w owns unit tiles 2w, 2w+1)
    float b1v[2], hqv[2], Vv[2];
#pragma unroll
    for (int q = 0; q < 2; ++q) {
        int u = (2 * w + q) * 16 + u0;
        b1v[q] = b1[u];
        hqv[q] = hq[b * U_ + u];
        Vv[q] = Vk[u];
    }

    float c1 = 0.f;
    const float* vbase = values + ((size_t)b * T_ + t0) * D_;

    stage_half(vbase, w, lane, Ah, Al);          // half 0

    for (int h = 0; h < 2; ++h) {
        __syncthreads();   // staging done (and m_s init for h=0)

        // ---- MFMA: wave w owns N-tiles {2w,2w+1}; mt in {0,1} ----
        f32x4 acc[2][2];
#pragma unroll
        for (int mt = 0; mt < 2; ++mt)
#pragma unroll
            for (int q = 0; q < 2; ++q) acc[mt][q] = (f32x4){0.f, 0.f, 0.f, 0.f};

#pragma unroll
        for (int kk = 0; kk < 8; ++kk) {
            bf16x8 bh[2], bl[2];
#pragma unroll
            for (int q = 0; q < 2; ++q) {
                int nn = 2 * w + q;
                int boff = ((kk * 8 + nn) * 64 + lane) * 8;
                bh[q] = __builtin_bit_cast(bf16x8, *(const s16x8*)&W1h[boff]);
                bl[q] = __builtin_bit_cast(bf16x8, *(const s16x8*)&W1l[boff]);
            }
#pragma unroll
            for (int mt = 0; mt < 2; ++mt) {
                int aoff = (mt * 8 + kk) * GRP_ + lane * 8;
                bf16x8 ah = __builtin_bit_cast(bf16x8, *(const s16x8*)&Ah[aoff]);
                bf16x8 al = __builtin_bit_cast(bf16x8, *(const s16x8*)&Al[aoff]);
#pragma unroll
                for (int q = 0; q < 2; ++q) {
                    acc[mt][q] = __builtin_amdgcn_mfma_f32_16x16x32_bf16(ah, bh[q], acc[mt][q], 0, 0, 0);
                    acc[mt][q] = __builtin_amdgcn_mfma_f32_16x16x32_bf16(ah, bl[q], acc[mt][q], 0, 0, 0);
                    acc[mt][q] = __builtin_amdgcn_mfma_f32_16x16x32_bf16(al, bh[q], acc[mt][q], 0, 0, 0);
                }
            }
        }

        // ---- epilogue: per-wave partial scores over its 32 units ----
#pragma unroll
        for (int mt = 0; mt < 2; ++mt) {
            float p[4];
#pragma unroll
            for (int i = 0; i < 4; ++i) {
                float z = 0.f;
#pragma unroll
                for (int q = 0; q < 2; ++q) {
                    float hpre = fmaxf(acc[mt][q][i] + b1v[q], 0.f) + hqv[q];
                    z += tanh_fast(hpre) * Vv[q];
                }
                p[i] = z;
            }
#pragma unroll
            for (int off = 1; off < 16; off <<= 1)
#pragma unroll
                for (int i = 0; i < 4; ++i) p[i] += __shfl_xor(p[i], off, 16);
            if (u0 == 0) {
                int base = mt * 16 + (lane >> 4) * 4;
#pragma unroll
                for (int i = 0; i < 4; ++i) scp[w][base + i] = p[i];
            }
        }
        __syncthreads();

        // ---- online softmax stats for this half (one 32-lane group) ----
        if (tid < 32) {
            float s = scp[0][tid] + scp[1][tid] + scp[2][tid] + scp[3][tid];
            sc_g[b * T_ + t0 + h * 32 + tid] = s;
            float mh = s;
#pragma unroll
            for (int off = 16; off >= 1; off >>= 1)
                mh = fmaxf(mh, __shfl_xor(mh, off, 32));
            float m_old = m_s;
            float m_new = fmaxf(m_old, mh);
            float e = __expf(s - m_new);
            esc[tid] = e;
            float lh = e;
#pragma unroll
            for (int off = 16; off >= 1; off >>= 1)
                lh += __shfl_xor(lh, off, 32);
            if (tid == 0) {
                alpha_s = __expf(m_old - m_new);
                l_s = l_s * alpha_s + lh;
                m_s = m_new;
            }
        }
        __syncthreads();

        // ---- ctx accumulate from global (L1/L2-hot), coalesced ----
        {
            c1 *= alpha_s;
            const float* vcol = vbase + (size_t)(h * 32) * D_ + tid;
#pragma unroll
            for (int tl = 0; tl < 32; ++tl)
                c1 = fmaf(esc[tl], vcol[(size_t)tl * D_], c1);
        }
        // overlap: stage next half while others still in ctx (no barrier
        // needed: ctx reads global+esc only; MFMA h finished pre-barrier)
        if (h == 0) stage_half(vbase + 32 * D_, w, lane, Ah, Al);
    }

    cp_g[((size_t)(b * NCH_ + c)) * D_ + tid] = c1;
    if (tid == 0) {
        st_g[(b * NCH_ + c) * 2 + 0] = m_s;
        st_g[(b * NCH_ + c) * 2 + 1] = l_s;
    }
}

// ---------------- k2: epilogue — attn (blocks 0..255) + ctx (256..287) -----
__global__ __launch_bounds__(256) void epilogue(
    const float* __restrict__ sc_g, const float* __restrict__ st_g,
    const float* __restrict__ cp_g, float* __restrict__ out)
{
    __shared__ float wcA[128];
    __shared__ float wm[4], wl[4];
    int blk = blockIdx.x, tid = threadIdx.x;
    int b = (blk < 256) ? (blk >> 3) : (blk - 256);

    float m_c = -1e30f, l_c = 0.f;
    if (tid < 128) {
        m_c = st_g[(b * NCH_ + tid) * 2 + 0];
        l_c = st_g[(b * NCH_ + tid) * 2 + 1];
    }
    float mm = m_c;
#pragma unroll
    for (int off = 32; off >= 1; off >>= 1) mm = fmaxf(mm, __shfl_xor(mm, off, 64));
    if ((tid & 63) == 0) wm[tid >> 6] = mm;
    __syncthreads();
    float M = fmaxf(fmaxf(wm[0], wm[1]), fmaxf(wm[2], wm[3]));
    float wc = (tid < 128) ? __expf(m_c - M) : 0.f;
    if (tid < 128) wcA[tid] = wc;
    float lw = l_c * wc;
#pragma unroll
    for (int off = 32; off >= 1; off >>= 1) lw += __shfl_xor(lw, off, 64);
    if ((tid & 63) == 0) wl[tid >> 6] = lw;
    __syncthreads();
    float invL = 1.f / (wl[0] + wl[1] + wl[2] + wl[3]);

    if (blk < 256) {
        int s8 = blk & 7;
        int t = s8 * 1024 + tid * 4;
        float4 s4 = *(const float4*)&sc_g[(size_t)b * T_ + t];
        float4 r;
        r.x = __expf(s4.x - M) * invL;
        r.y = __expf(s4.y - M) * invL;
        r.z = __expf(s4.z - M) * invL;
        r.w = __expf(s4.w - M) * invL;
        *(float4*)&out[B_ * D_ + (size_t)b * T_ + t] = r;
    } else {
        float a = 0.f;
        const float* p = cp_g + (size_t)b * NCH_ * D_ + tid;
#pragma unroll 8
        for (int c2 = 0; c2 < NCH_; ++c2)
            a = fmaf(wcA[c2], p[(size_t)c2 * D_], a);
        out[b * D_ + tid] = a * invL;
    }
}

// ---------------- launch ----------------
extern "C" void kernel_launch(void* const* d_in, const int* in_sizes, int n_in,
                              void* d_out, int out_size, void* d_ws, size_t ws_size,
                              hipStream_t stream)
{
    const float* query = (const float*)d_in[0];
    const float* values = (const float*)d_in[1];
    const float* W1 = (const float*)d_in[2];
    const float* b1 = (const float*)d_in[3];
    const float* W2 = (const float*)d_in[4];
    const float* b2 = (const float*)d_in[5];
    const float* Vk = (const float*)d_in[6];
    // d_in[7] = V_bias: constant score shift, cancels in softmax.
    float* out = (float*)d_out;
    char* ws = (char*)d_ws;

    // ws layout (bytes), total 5,423,104
    float* scores = (float*)(ws + 0);                  // B*T*4       = 1048576
    float* hq     = (float*)(ws + 1048576);            // B*U*4       = 16384
    float* stats  = (float*)(ws + 1064960);            // B*128*2*4   = 32768
    float* ctxp   = (float*)(ws + 1097728);            // B*128*256*4 = 4194304
    unsigned short* W1h = (unsigned short*)(ws + 5292032);   // 65536
    unsigned short* W1l = (unsigned short*)(ws + 5357568);   // 65536

    prep<<<160, 256, 0, stream>>>(W1, query, W2, b2, W1h, W1l, hq);
    score_ctx<<<B_ * NCH_, 256, 0, stream>>>(values, W1h, W1l, hq, b1, Vk,
                                             scores, stats, ctxp);
    epilogue<<<288, 256, 0, stream>>>(scores, stats, ctxp, out);
}